// Round 5
// baseline (260.448 us; speedup 1.0000x reference)
//
#include <hip/hip_runtime.h>
#include <hip/hip_bf16.h>
#include <hip/hip_fp16.h>

typedef _Float16 half8 __attribute__((ext_vector_type(8)));
typedef _Float16 half4v __attribute__((ext_vector_type(4)));
typedef float float4v __attribute__((ext_vector_type(4)));

#define MFMA_F16(a, b, c) __builtin_amdgcn_mfma_f32_16x16x32_f16((a), (b), (c), 0, 0, 0)

// Async global->LDS DMA, 16B per lane. LDS dest = wave-uniform base + lane*16.
#define GLDS16(gp, lp) \
    __builtin_amdgcn_global_load_lds((const __attribute__((address_space(1))) unsigned int*)(gp), \
                                     (__attribute__((address_space(3))) unsigned int*)(lp), 16, 0, 0)

#define BATCH 8
#define SEQ   2048
#define DIM   1024
#define QD    128
#define BT    (BATCH * SEQ)          // 16384
#define NSPLIT 8
#define KSPAN (SEQ / NSPLIT)         // 256

// 16-lane all-lanes max reduction via DPP — pure VALU, stays off the LDS pipe.
__device__ __forceinline__ float dpp_max16(float x) {
    int v;
    v = __builtin_amdgcn_update_dpp(0, __float_as_int(x), 0xB1, 0xF, 0xF, false);  // quad_perm [1,0,3,2]
    x = fmaxf(x, __int_as_float(v));
    v = __builtin_amdgcn_update_dpp(0, __float_as_int(x), 0x4E, 0xF, 0xF, false);  // quad_perm [2,3,0,1]
    x = fmaxf(x, __int_as_float(v));
    v = __builtin_amdgcn_update_dpp(0, __float_as_int(x), 0x141, 0xF, 0xF, false); // row_half_mirror
    x = fmaxf(x, __int_as_float(v));
    v = __builtin_amdgcn_update_dpp(0, __float_as_int(x), 0x140, 0xF, 0xF, false); // row_mirror
    x = fmaxf(x, __int_as_float(v));
    return x;
}

// ---------------------------------------------------------------------------
// fp32 -> fp16 convert for x and the three W's, one kernel (BW-bound).
// ---------------------------------------------------------------------------
#define XN4 (BT * DIM / 4)           // 4194304 float4s in x
#define WN4 (3 * QD * DIM / 4)       // 98304 float4s in Wq+Wk+Wv

__global__ __launch_bounds__(256) void cvt_kernel(
    const float* __restrict__ x,
    const float* __restrict__ Wq,
    const float* __restrict__ Wk,
    const float* __restrict__ Wv,
    _Float16* __restrict__ xh,
    _Float16* __restrict__ Wh)
{
    int i = blockIdx.x * 256 + threadIdx.x;
    if (i < XN4) {
        float4 f = ((const float4*)x)[i];
        half4v h = {(_Float16)f.x, (_Float16)f.y, (_Float16)f.z, (_Float16)f.w};
        ((half4v*)xh)[i] = h;
    } else {
        int j = i - XN4;                       // 0 .. WN4-1
        int which = j >> 15;                   // 32768 float4 per W
        int o = j & 32767;
        const float* src = (which == 0) ? Wq : ((which == 1) ? Wk : Wv);
        float4 f = ((const float4*)src)[o];
        half4v h = {(_Float16)f.x, (_Float16)f.y, (_Float16)f.z, (_Float16)f.w};
        ((half4v*)Wh)[j] = h;
    }
}

// ---------------------------------------------------------------------------
// Projection: 64x128 tile, BK=128 (8 K-iters -> half the barrier drains of
// BK=64). global_load_lds staging into XOR-swizzled LDS (2-way-only bank
// aliasing on ds_read_b128 = free). Grid 256x3 = 768 = exactly 3 blocks/CU.
// LDS 48 KB -> 3 blocks/CU resident.
// ---------------------------------------------------------------------------
__global__ __launch_bounds__(256, 3) void proj_kernel(
    const _Float16* __restrict__ xh,     // (B*T, 1024)
    const _Float16* __restrict__ Wh,     // 3 x (128, 1024)
    _Float16* __restrict__ q_out,        // (B*T, 128)
    _Float16* __restrict__ k_out,        // (B*T, 128)
    _Float16* __restrict__ vt_out)       // (B, 128, T)
{
    __shared__ _Float16 As[64 * 128];    // 16 KB, swizzled, 64 rows x 16 groups
    __shared__ _Float16 Bs[128 * 128];   // 32 KB, swizzled, 128 rows x 16 groups

    const int tid  = threadIdx.x;
    const int lane = tid & 63;
    const int wave = tid >> 6;
    const int quad = lane >> 4;
    const int l15  = lane & 15;
    const int wr   = wave >> 1;          // row half (32 rows)
    const int wc   = wave & 1;           // col half (64 cols)

    const int which = blockIdx.y;
    const _Float16* W = Wh + (size_t)which * QD * DIM;
    const int row0 = blockIdx.x * 64;

    float4v acc[2][4];
#pragma unroll
    for (int rf = 0; rf < 2; rf++)
#pragma unroll
        for (int n = 0; n < 4; n++)
            acc[rf][n] = (float4v){0.f, 0.f, 0.f, 0.f};

    for (int kk = 0; kk < DIM; kk += 128) {
        __syncthreads();
        // A: 64x128 halfs = 1024 16B chunks; 4 DMA/wave.
#pragma unroll
        for (int c = 0; c < 4; c++) {
            int ci = wave * 256 + c * 64 + lane;
            int r  = ci >> 4;
            int gs = ci & 15;
            int g  = (gs & 8) | ((gs ^ r) & 7);
            GLDS16(xh + (size_t)(row0 + r) * DIM + kk + g * 8, &As[(wave * 256 + c * 64) * 8]);
        }
        // B: 128x128 halfs = 2048 chunks; 8 DMA/wave.
#pragma unroll
        for (int c = 0; c < 8; c++) {
            int ci = wave * 512 + c * 64 + lane;
            int r  = ci >> 4;
            int gs = ci & 15;
            int g  = (gs & 8) | ((gs ^ r) & 7);
            GLDS16(W + (size_t)r * DIM + kk + g * 8, &Bs[(wave * 512 + c * 64) * 8]);
        }
        __syncthreads();

#pragma unroll
        for (int kc = 0; kc < 4; kc++) {
            half8 af[2], bf[4];
#pragma unroll
            for (int rf = 0; rf < 2; rf++) {
                int r = wr * 32 + rf * 16 + l15;
                int g = kc * 4 + quad;
                int gp = (g & 8) | ((g ^ r) & 7);
                af[rf] = *(const half8*)&As[r * 128 + gp * 8];
            }
#pragma unroll
            for (int n = 0; n < 4; n++) {
                int r = wc * 64 + n * 16 + l15;
                int g = kc * 4 + quad;
                int gp = (g & 8) | ((g ^ r) & 7);
                bf[n] = *(const half8*)&Bs[r * 128 + gp * 8];
            }
#pragma unroll
            for (int rf = 0; rf < 2; rf++)
#pragma unroll
                for (int n = 0; n < 4; n++)
                    acc[rf][n] = MFMA_F16(af[rf], bf[n], acc[rf][n]);
        }
    }

    // Epilogue. C layout: col = l15, row = quad*4 + reg.
    if (which == 2) {
#pragma unroll
        for (int rf = 0; rf < 2; rf++) {
            int grow0 = row0 + wr * 32 + rf * 16 + quad * 4;
            int b  = grow0 >> 11;
            int t0 = grow0 & 2047;
#pragma unroll
            for (int n = 0; n < 4; n++) {
                int col = wc * 64 + n * 16 + l15;
                half4v h;
#pragma unroll
                for (int r = 0; r < 4; r++) h[r] = (_Float16)acc[rf][n][r];
                *(half4v*)&vt_out[((size_t)(b * QD + col)) * SEQ + t0] = h;
            }
        }
    } else {
        _Float16* out = (which == 0) ? q_out : k_out;
#pragma unroll
        for (int rf = 0; rf < 2; rf++) {
            int grow0 = row0 + wr * 32 + rf * 16 + quad * 4;
#pragma unroll
            for (int n = 0; n < 4; n++) {
                int col = wc * 64 + n * 16 + l15;
#pragma unroll
                for (int r = 0; r < 4; r++)
                    out[(size_t)(grow0 + r) * QD + col] = (_Float16)acc[rf][n][r];
            }
        }
    }
}

// ---------------------------------------------------------------------------
// Flash attention. Block = 128 q-rows (4 waves x 32 rows), key blocks of 64,
// key-split 8 over blockIdx.z -> grid 1024 = exactly 4 blocks/CU.
// P slab ALIASES Ks (extra barrier after QK makes it safe) -> LDS 32.25 KB.
// ---------------------------------------------------------------------------
__global__ __launch_bounds__(256, 4) void attn_kernel(
    const _Float16* __restrict__ q,    // (B*T, 128)
    const _Float16* __restrict__ k,    // (B*T, 128)
    const _Float16* __restrict__ vt,   // (B, 128, T)
    const int* __restrict__ mask,      // (B*T)
    _Float16* __restrict__ Op,         // (NSPLIT, B*T, 128)
    float2* __restrict__ ml)           // (NSPLIT, B*T)
{
    __shared__ _Float16 KPs[64 * 128];     // 16 KB: K tile during QK, P slabs during PV
    __shared__ _Float16 Vs[128 * 64];      // 16 KB swizzled: 128d x 64 keys
    __shared__ int Ms[64];

    const int tid  = threadIdx.x;
    const int lane = tid & 63;
    const int wave = tid >> 6;
    const int quad = lane >> 4;
    const int l15  = lane & 15;

    const int b  = blockIdx.y;
    const int z  = blockIdx.z;
    const int rowbase = blockIdx.x * 128 + wave * 32;

    half8 qf[2][4];
#pragma unroll
    for (int rf = 0; rf < 2; rf++) {
        const _Float16* qrow = q + ((size_t)(b * SEQ + rowbase + rf * 16 + l15)) * QD + quad * 8;
#pragma unroll
        for (int kc = 0; kc < 4; kc++)
            qf[rf][kc] = *(const half8*)(qrow + kc * 32);
    }

    const half8 onesv = {(_Float16)1, (_Float16)1, (_Float16)1, (_Float16)1,
                         (_Float16)1, (_Float16)1, (_Float16)1, (_Float16)1};

    float4v oacc[2][8];
#pragma unroll
    for (int rf = 0; rf < 2; rf++)
#pragma unroll
        for (int n = 0; n < 8; n++)
            oacc[rf][n] = (float4v){0.f, 0.f, 0.f, 0.f};
    float4v lacc[2] = {(float4v){0.f, 0.f, 0.f, 0.f}, (float4v){0.f, 0.f, 0.f, 0.f}};
    float mrow[2][4];
#pragma unroll
    for (int rf = 0; rf < 2; rf++)
#pragma unroll
        for (int r = 0; r < 4; r++) mrow[rf][r] = -1e30f;

    _Float16* Pw = &KPs[wave * 32 * 64];   // wave-private 4 KB slab (aliases Ks)

    for (int sb = z * KSPAN; sb < z * KSPAN + KSPAN; sb += 64) {
        __syncthreads();   // #1: prior iter's PV reads of KPs/Vs complete
        // K: 64 keys x 128d = 1024 chunks; 4 DMA/wave, swizzled dest.
#pragma unroll
        for (int c = 0; c < 4; c++) {
            int ci = wave * 256 + c * 64 + lane;
            int r  = ci >> 4;                       // key
            int gs = ci & 15;
            int g  = (gs & 8) | ((gs ^ r) & 7);
            GLDS16(k + ((size_t)(b * SEQ + sb + r)) * QD + g * 8, &KPs[(wave * 256 + c * 64) * 8]);
        }
        // V^T: 128d x 64 keys = 1024 chunks; 4 DMA/wave.
#pragma unroll
        for (int c = 0; c < 4; c++) {
            int ci = wave * 256 + c * 64 + lane;
            int r  = ci >> 3;                       // d
            int g  = ((ci & 7) ^ r) & 7;
            GLDS16(vt + ((size_t)(b * QD + r)) * SEQ + sb + g * 8, &Vs[(wave * 256 + c * 64) * 8]);
        }
        if (tid < 64) Ms[tid] = mask[b * SEQ + sb + tid];
        __syncthreads();   // #2: staging visible

        // S = Q K^T : 32 rows x 64 keys per wave, C layout
        float4v sacc[2][4];
#pragma unroll
        for (int rf = 0; rf < 2; rf++)
#pragma unroll
            for (int j = 0; j < 4; j++)
                sacc[rf][j] = (float4v){0.f, 0.f, 0.f, 0.f};
#pragma unroll
        for (int kc = 0; kc < 4; kc++) {
            half8 kf[4];
#pragma unroll
            for (int j = 0; j < 4; j++) {
                int r  = j * 16 + l15;
                int g  = kc * 4 + quad;
                int gs = (g & 8) | ((g ^ r) & 7);
                kf[j] = *(const half8*)&KPs[r * 128 + gs * 8];
            }
#pragma unroll
            for (int rf = 0; rf < 2; rf++)
#pragma unroll
                for (int j = 0; j < 4; j++)
                    sacc[rf][j] = MFMA_F16(qf[rf][kc], kf[j], sacc[rf][j]);
        }

        // mask + row-max + online-softmax scale (register/DPP only)
        float alpha[2][4];
#pragma unroll
        for (int rf = 0; rf < 2; rf++) {
            float rmax[4] = {-1e30f, -1e30f, -1e30f, -1e30f};
#pragma unroll
            for (int j = 0; j < 4; j++) {
                bool m_ok = (Ms[j * 16 + l15] != 0);
#pragma unroll
                for (int r = 0; r < 4; r++) {
                    float s = m_ok ? sacc[rf][j][r] : -1e30f;
                    sacc[rf][j][r] = s;
                    rmax[r] = fmaxf(rmax[r], s);
                }
            }
#pragma unroll
            for (int r = 0; r < 4; r++) {
                float rm = dpp_max16(rmax[r]);
                float mnew = fmaxf(mrow[rf][r], rm);
                alpha[rf][r] = __expf(mrow[rf][r] - mnew);
                mrow[rf][r] = mnew;
            }
        }

        // rescale accumulators (VALU, overlaps other waves' LDS work)
#pragma unroll
        for (int rf = 0; rf < 2; rf++) {
#pragma unroll
            for (int n = 0; n < 8; n++)
#pragma unroll
                for (int r = 0; r < 4; r++)
                    oacc[rf][n][r] *= alpha[rf][r];
#pragma unroll
            for (int r = 0; r < 4; r++) lacc[rf][r] *= alpha[rf][r];
        }

        __syncthreads();   // #3: all waves' QK reads of KPs done -> safe to write P

        // p = exp(s - m) -> wave-private swizzled slab (C-layout write)
#pragma unroll
        for (int rf = 0; rf < 2; rf++)
#pragma unroll
            for (int j = 0; j < 4; j++) {
                int col = j * 16 + l15;
                int gc  = col >> 3;
#pragma unroll
                for (int r = 0; r < 4; r++) {
                    int m  = rf * 16 + quad * 4 + r;
                    int gs = (gc ^ m) & 7;
                    float s = sacc[rf][j][r];
                    float p = (s > -1e29f) ? __expf(s - mrow[rf][r]) : 0.f;
                    Pw[m * 64 + gs * 8 + (col & 7)] = (_Float16)p;
                }
            }

        // O += P V ; l += P 1
#pragma unroll
        for (int kc = 0; kc < 2; kc++) {
            half8 pf[2];
#pragma unroll
            for (int rf = 0; rf < 2; rf++) {
                int m  = rf * 16 + l15;
                int gs = ((kc * 4 + quad) ^ m) & 7;
                pf[rf] = *(const half8*)&Pw[m * 64 + gs * 8];
            }
#pragma unroll
            for (int n = 0; n < 8; n++) {
                int r  = n * 16 + l15;
                int gs = ((kc * 4 + quad) ^ r) & 7;
                half8 vf = *(const half8*)&Vs[r * 64 + gs * 8];
#pragma unroll
                for (int rf = 0; rf < 2; rf++)
                    oacc[rf][n] = MFMA_F16(pf[rf], vf, oacc[rf][n]);
            }
#pragma unroll
            for (int rf = 0; rf < 2; rf++)
                lacc[rf] = MFMA_F16(pf[rf], onesv, lacc[rf]);
        }
    }

    // Epilogue: fp16 unnormalized partials + (m, l)
    _Float16* Oz = Op + (size_t)z * BT * QD;
#pragma unroll
    for (int rf = 0; rf < 2; rf++) {
#pragma unroll
        for (int n = 0; n < 8; n++) {
            int col = n * 16 + l15;
#pragma unroll
            for (int r = 0; r < 4; r++) {
                int row = rowbase + rf * 16 + quad * 4 + r;
                Oz[((size_t)(b * SEQ + row)) * QD + col] = (_Float16)oacc[rf][n][r];
            }
        }
        if (l15 == 0) {
#pragma unroll
            for (int r = 0; r < 4; r++) {
                int row = rowbase + rf * 16 + quad * 4 + r;
                ml[(size_t)z * BT + b * SEQ + row] = make_float2(mrow[rf][r], lacc[rf][r]);
            }
        }
    }
}

// ---------------------------------------------------------------------------
// Merge NSPLIT fp16 partials. 16 threads/row, 8 cols each.
// ---------------------------------------------------------------------------
__global__ __launch_bounds__(256) void merge_kernel(
    const _Float16* __restrict__ Op,
    const float2* __restrict__ ml,
    float* __restrict__ out)
{
    int gid = blockIdx.x * 256 + threadIdx.x;
    int row = gid >> 4;
    int c8  = (gid & 15) * 8;

    float2 a[NSPLIT];
    float m = -3.0e38f;
#pragma unroll
    for (int s = 0; s < NSPLIT; s++) { a[s] = ml[(size_t)s * BT + row]; m = fmaxf(m, a[s].x); }
    float sc[NSPLIT];
    float denom = 0.f;
#pragma unroll
    for (int s = 0; s < NSPLIT; s++) { sc[s] = __expf(a[s].x - m); denom += sc[s] * a[s].y; }
    float inv = (denom > 0.f) ? (1.0f / denom) : 0.f;

    float acc[8] = {0, 0, 0, 0, 0, 0, 0, 0};
#pragma unroll
    for (int s = 0; s < NSPLIT; s++) {
        half8 o = *(const half8*)&Op[(size_t)s * BT * QD + (size_t)row * QD + c8];
#pragma unroll
        for (int e = 0; e < 8; e++) acc[e] += (float)o[e] * sc[s];
    }
    float4 lo = make_float4(acc[0] * inv, acc[1] * inv, acc[2] * inv, acc[3] * inv);
    float4 hi = make_float4(acc[4] * inv, acc[5] * inv, acc[6] * inv, acc[7] * inv);
    *(float4*)&out[(size_t)row * QD + c8] = lo;
    *(float4*)&out[(size_t)row * QD + c8 + 4] = hi;
}

extern "C" void kernel_launch(void* const* d_in, const int* in_sizes, int n_in,
                              void* d_out, int out_size, void* d_ws, size_t ws_size,
                              hipStream_t stream) {
    const float* x    = (const float*)d_in[0];
    const int*   mask = (const int*)d_in[1];
    const float* Wq   = (const float*)d_in[2];
    const float* Wk   = (const float*)d_in[3];
    const float* Wv   = (const float*)d_in[4];
    float* out = (float*)d_out;

    char* p = (char*)d_ws;
    _Float16* xh  = (_Float16*)p; p += (size_t)BT * DIM * 2;        // 32 MB
    _Float16* Wh  = (_Float16*)p; p += (size_t)3 * QD * DIM * 2;    // 768 KB
    _Float16* qb  = (_Float16*)p; p += (size_t)BT * QD * 2;         // 4 MB
    _Float16* kb  = (_Float16*)p; p += (size_t)BT * QD * 2;         // 4 MB
    _Float16* vtb = (_Float16*)p; p += (size_t)BT * QD * 2;         // 4 MB
    _Float16* Op  = (_Float16*)p; p += (size_t)NSPLIT * BT * QD * 2;// 32 MB
    float2*   ml  = (float2*)p;                                     // 1 MB

    cvt_kernel<<<dim3((XN4 + WN4) / 256), 256, 0, stream>>>(x, Wq, Wk, Wv, xh, Wh);
    proj_kernel<<<dim3(BT / 64, 3), 256, 0, stream>>>(xh, Wh, qb, kb, vtb);
    attn_kernel<<<dim3(SEQ / 128, BATCH, NSPLIT), 256, 0, stream>>>(qb, kb, vtb, mask, Op, ml);
    merge_kernel<<<dim3(BT * 16 / 256), 256, 0, stream>>>(Op, ml, out);
}

// Round 6
// 254.939 us; speedup vs baseline: 1.0216x; 1.0216x over previous
//
#include <hip/hip_runtime.h>
#include <hip/hip_bf16.h>
#include <hip/hip_fp16.h>

typedef _Float16 half8 __attribute__((ext_vector_type(8)));
typedef _Float16 half4v __attribute__((ext_vector_type(4)));
typedef float float4v __attribute__((ext_vector_type(4)));

#define MFMA_F16(a, b, c) __builtin_amdgcn_mfma_f32_16x16x32_f16((a), (b), (c), 0, 0, 0)

// Async global->LDS DMA, 16B per lane. LDS dest = wave-uniform base + lane*16.
#define GLDS16(gp, lp) \
    __builtin_amdgcn_global_load_lds((const __attribute__((address_space(1))) unsigned int*)(gp), \
                                     (__attribute__((address_space(3))) unsigned int*)(lp), 16, 0, 0)

#define BATCH 8
#define SEQ   2048
#define DIM   1024
#define QD    128
#define BT    (BATCH * SEQ)          // 16384
#define NSPLIT 8
#define KSPAN (SEQ / NSPLIT)         // 256

// 16-lane all-lanes max reduction via DPP — pure VALU, stays off the LDS pipe.
__device__ __forceinline__ float dpp_max16(float x) {
    int v;
    v = __builtin_amdgcn_update_dpp(0, __float_as_int(x), 0xB1, 0xF, 0xF, false);  // quad_perm [1,0,3,2]
    x = fmaxf(x, __int_as_float(v));
    v = __builtin_amdgcn_update_dpp(0, __float_as_int(x), 0x4E, 0xF, 0xF, false);  // quad_perm [2,3,0,1]
    x = fmaxf(x, __int_as_float(v));
    v = __builtin_amdgcn_update_dpp(0, __float_as_int(x), 0x141, 0xF, 0xF, false); // row_half_mirror
    x = fmaxf(x, __int_as_float(v));
    v = __builtin_amdgcn_update_dpp(0, __float_as_int(x), 0x140, 0xF, 0xF, false); // row_mirror
    x = fmaxf(x, __int_as_float(v));
    return x;
}

// ---------------------------------------------------------------------------
// fp32 -> fp16 convert for x and the three W's, one kernel (BW-bound).
// ---------------------------------------------------------------------------
#define XN4 (BT * DIM / 4)           // 4194304 float4s in x
#define WN4 (3 * QD * DIM / 4)       // 98304 float4s in Wq+Wk+Wv

__global__ __launch_bounds__(256) void cvt_kernel(
    const float* __restrict__ x,
    const float* __restrict__ Wq,
    const float* __restrict__ Wk,
    const float* __restrict__ Wv,
    _Float16* __restrict__ xh,
    _Float16* __restrict__ Wh)
{
    int i = blockIdx.x * 256 + threadIdx.x;
    if (i < XN4) {
        float4 f = ((const float4*)x)[i];
        half4v h = {(_Float16)f.x, (_Float16)f.y, (_Float16)f.z, (_Float16)f.w};
        ((half4v*)xh)[i] = h;
    } else {
        int j = i - XN4;                       // 0 .. WN4-1
        int which = j >> 15;                   // 32768 float4 per W
        int o = j & 32767;
        const float* src = (which == 0) ? Wq : ((which == 1) ? Wk : Wv);
        float4 f = ((const float4*)src)[o];
        half4v h = {(_Float16)f.x, (_Float16)f.y, (_Float16)f.z, (_Float16)f.w};
        ((half4v*)Wh)[j] = h;
    }
}

// ---------------------------------------------------------------------------
// Projection (R4 config): 64x128 tile, BK=64, global_load_lds staging into
// XOR-swizzled LDS. Grid 256 x 3 = 768 blocks = exactly 3/CU. LDS 24 KB.
// ---------------------------------------------------------------------------
__global__ __launch_bounds__(256, 3) void proj_kernel(
    const _Float16* __restrict__ xh,     // (B*T, 1024)
    const _Float16* __restrict__ Wh,     // 3 x (128, 1024)
    _Float16* __restrict__ q_out,        // (B*T, 128)
    _Float16* __restrict__ k_out,        // (B*T, 128)
    _Float16* __restrict__ vt_out)       // (B, 128, T)
{
    __shared__ _Float16 As[64 * 64];     // 8 KB, swizzled row-major 64 x 64
    __shared__ _Float16 Bs[128 * 64];    // 16 KB

    const int tid  = threadIdx.x;
    const int lane = tid & 63;
    const int wave = tid >> 6;
    const int quad = lane >> 4;
    const int l15  = lane & 15;
    const int wr   = wave >> 1;          // 0..1 : row half (32 rows)
    const int wc   = wave & 1;           // 0..1 : col half (64 cols)

    const int which = blockIdx.y;
    const _Float16* W = Wh + (size_t)which * QD * DIM;
    const int row0 = blockIdx.x * 64;

    float4v acc[2][4];
#pragma unroll
    for (int rf = 0; rf < 2; rf++)
#pragma unroll
        for (int n = 0; n < 4; n++)
            acc[rf][n] = (float4v){0.f, 0.f, 0.f, 0.f};

    for (int kk = 0; kk < DIM; kk += 64) {
        __syncthreads();
        // A: 512 chunks of 16B; 2 DMA calls per wave.
#pragma unroll
        for (int c = 0; c < 2; c++) {
            int ci = wave * 128 + c * 64 + lane;          // 0..511
            int r  = ci >> 3;
            int g  = (ci & 7) ^ (r & 7);                  // un-swizzle on the global side
            GLDS16(xh + (size_t)(row0 + r) * DIM + kk + g * 8, &As[(wave * 128 + c * 64) * 8]);
        }
        // B: 1024 chunks; 4 DMA calls per wave.
#pragma unroll
        for (int c = 0; c < 4; c++) {
            int ci = wave * 256 + c * 64 + lane;          // 0..1023
            int r  = ci >> 3;
            int g  = (ci & 7) ^ (r & 7);
            GLDS16(W + (size_t)r * DIM + kk + g * 8, &Bs[(wave * 256 + c * 64) * 8]);
        }
        __syncthreads();

        half8 af[2][2], bf[4][2];
#pragma unroll
        for (int rf = 0; rf < 2; rf++)
#pragma unroll
            for (int kc = 0; kc < 2; kc++) {
                int r = wr * 32 + rf * 16 + l15;
                int g = (kc * 4 + quad) ^ (r & 7);
                af[rf][kc] = *(const half8*)&As[r * 64 + g * 8];
            }
#pragma unroll
        for (int n = 0; n < 4; n++)
#pragma unroll
            for (int kc = 0; kc < 2; kc++) {
                int r = wc * 64 + n * 16 + l15;
                int g = (kc * 4 + quad) ^ (r & 7);
                bf[n][kc] = *(const half8*)&Bs[r * 64 + g * 8];
            }
#pragma unroll
        for (int kc = 0; kc < 2; kc++)
#pragma unroll
            for (int rf = 0; rf < 2; rf++)
#pragma unroll
                for (int n = 0; n < 4; n++)
                    acc[rf][n] = MFMA_F16(af[rf][kc], bf[n][kc], acc[rf][n]);
    }

    // Epilogue. C layout: col = l15, row = quad*4 + reg.
    if (which == 2) {
#pragma unroll
        for (int rf = 0; rf < 2; rf++) {
            int grow0 = row0 + wr * 32 + rf * 16 + quad * 4;
            int b  = grow0 >> 11;
            int t0 = grow0 & 2047;
#pragma unroll
            for (int n = 0; n < 4; n++) {
                int col = wc * 64 + n * 16 + l15;
                half4v h;
#pragma unroll
                for (int r = 0; r < 4; r++) h[r] = (_Float16)acc[rf][n][r];
                *(half4v*)&vt_out[((size_t)(b * QD + col)) * SEQ + t0] = h;
            }
        }
    } else {
        _Float16* out = (which == 0) ? q_out : k_out;
#pragma unroll
        for (int rf = 0; rf < 2; rf++) {
            int grow0 = row0 + wr * 32 + rf * 16 + quad * 4;
#pragma unroll
            for (int n = 0; n < 4; n++) {
                int col = wc * 64 + n * 16 + l15;
#pragma unroll
                for (int r = 0; r < 4; r++)
                    out[(size_t)(grow0 + r) * QD + col] = (_Float16)acc[rf][n][r];
            }
        }
    }
}

// ---------------------------------------------------------------------------
// Flash attention. 1-D grid of 1024 blocks; batch = blockIdx.x & 7 so the
// round-robin workgroup->XCD dispatch pins each batch to one XCD (per-XCD
// working set = 1.5 MB q+k+vt < 4 MB L2). Block = 128 q-rows (4 waves x 32),
// key blocks of 64, key-split 8. P slab aliases Ks (LDS 32.25 KB -> 4/CU).
// Epilogue repacks O through LDS for full-line half8 stores.
// ---------------------------------------------------------------------------
__global__ __launch_bounds__(256, 4) void attn_kernel(
    const _Float16* __restrict__ q,    // (B*T, 128)
    const _Float16* __restrict__ k,    // (B*T, 128)
    const _Float16* __restrict__ vt,   // (B, 128, T)
    const int* __restrict__ mask,      // (B*T)
    _Float16* __restrict__ Op,         // (NSPLIT, B*T, 128)
    float2* __restrict__ ml)           // (NSPLIT, B*T)
{
    __shared__ _Float16 Smem[64 * 128 + 128 * 64];   // 32 KB: K|P slabs + V
    __shared__ int Ms[64];
    _Float16* KPs = Smem;                  // 16 KB: K tile during QK, P slabs during PV
    _Float16* Vs  = Smem + 64 * 128;       // 16 KB: 128d x 64 keys, swizzled

    const int tid  = threadIdx.x;
    const int lane = tid & 63;
    const int wave = tid >> 6;
    const int quad = lane >> 4;
    const int l15  = lane & 15;

    const int id  = blockIdx.x;            // 0..1023
    const int b   = id & 7;                // XCD-pinned batch
    const int rem = id >> 3;
    const int z   = rem & 7;
    const int xt  = rem >> 3;              // 0..15
    const int rowbase = xt * 128 + wave * 32;

    half8 qf[2][4];
#pragma unroll
    for (int rf = 0; rf < 2; rf++) {
        const _Float16* qrow = q + ((size_t)(b * SEQ + rowbase + rf * 16 + l15)) * QD + quad * 8;
#pragma unroll
        for (int kc = 0; kc < 4; kc++)
            qf[rf][kc] = *(const half8*)(qrow + kc * 32);
    }

    const half8 onesv = {(_Float16)1, (_Float16)1, (_Float16)1, (_Float16)1,
                         (_Float16)1, (_Float16)1, (_Float16)1, (_Float16)1};

    float4v oacc[2][8];
#pragma unroll
    for (int rf = 0; rf < 2; rf++)
#pragma unroll
        for (int n = 0; n < 8; n++)
            oacc[rf][n] = (float4v){0.f, 0.f, 0.f, 0.f};
    float4v lacc[2] = {(float4v){0.f, 0.f, 0.f, 0.f}, (float4v){0.f, 0.f, 0.f, 0.f}};
    float mrow[2][4];
#pragma unroll
    for (int rf = 0; rf < 2; rf++)
#pragma unroll
        for (int r = 0; r < 4; r++) mrow[rf][r] = -1e30f;

    _Float16* Pw = &KPs[wave * 32 * 64];   // wave-private 4 KB slab (aliases Ks)

    for (int sb = z * KSPAN; sb < z * KSPAN + KSPAN; sb += 64) {
        __syncthreads();   // #1: prior iter's PV reads of KPs/Vs complete
        // K: 64 keys x 128d = 1024 chunks; 4 DMA/wave, swizzled dest.
#pragma unroll
        for (int c = 0; c < 4; c++) {
            int ci = wave * 256 + c * 64 + lane;
            int r  = ci >> 4;                       // key
            int gs = ci & 15;
            int g  = (gs & 8) | ((gs ^ r) & 7);
            GLDS16(k + ((size_t)(b * SEQ + sb + r)) * QD + g * 8, &KPs[(wave * 256 + c * 64) * 8]);
        }
        // V^T: 128d x 64 keys = 1024 chunks; 4 DMA/wave.
#pragma unroll
        for (int c = 0; c < 4; c++) {
            int ci = wave * 256 + c * 64 + lane;
            int r  = ci >> 3;                       // d
            int g  = ((ci & 7) ^ r) & 7;
            GLDS16(vt + ((size_t)(b * QD + r)) * SEQ + sb + g * 8, &Vs[(wave * 256 + c * 64) * 8]);
        }
        if (tid < 64) Ms[tid] = mask[b * SEQ + sb + tid];
        __syncthreads();   // #2: staging visible

        // S = Q K^T : 32 rows x 64 keys per wave, C layout
        float4v sacc[2][4];
#pragma unroll
        for (int rf = 0; rf < 2; rf++)
#pragma unroll
            for (int j = 0; j < 4; j++)
                sacc[rf][j] = (float4v){0.f, 0.f, 0.f, 0.f};
#pragma unroll
        for (int kc = 0; kc < 4; kc++) {
            half8 kf[4];
#pragma unroll
            for (int j = 0; j < 4; j++) {
                int r  = j * 16 + l15;
                int g  = kc * 4 + quad;
                int gs = (g & 8) | ((g ^ r) & 7);
                kf[j] = *(const half8*)&KPs[r * 128 + gs * 8];
            }
#pragma unroll
            for (int rf = 0; rf < 2; rf++)
#pragma unroll
                for (int j = 0; j < 4; j++)
                    sacc[rf][j] = MFMA_F16(qf[rf][kc], kf[j], sacc[rf][j]);
        }

        // mask + row-max + online-softmax scale (register/DPP only)
        float alpha[2][4];
#pragma unroll
        for (int rf = 0; rf < 2; rf++) {
            float rmax[4] = {-1e30f, -1e30f, -1e30f, -1e30f};
#pragma unroll
            for (int j = 0; j < 4; j++) {
                bool m_ok = (Ms[j * 16 + l15] != 0);
#pragma unroll
                for (int r = 0; r < 4; r++) {
                    float s = m_ok ? sacc[rf][j][r] : -1e30f;
                    sacc[rf][j][r] = s;
                    rmax[r] = fmaxf(rmax[r], s);
                }
            }
#pragma unroll
            for (int r = 0; r < 4; r++) {
                float rm = dpp_max16(rmax[r]);
                float mnew = fmaxf(mrow[rf][r], rm);
                alpha[rf][r] = __expf(mrow[rf][r] - mnew);
                mrow[rf][r] = mnew;
            }
        }

        // rescale accumulators (VALU, overlaps other waves' LDS work)
#pragma unroll
        for (int rf = 0; rf < 2; rf++) {
#pragma unroll
            for (int n = 0; n < 8; n++)
#pragma unroll
                for (int r = 0; r < 4; r++)
                    oacc[rf][n][r] *= alpha[rf][r];
#pragma unroll
            for (int r = 0; r < 4; r++) lacc[rf][r] *= alpha[rf][r];
        }

        __syncthreads();   // #3: all waves' QK reads of KPs done -> safe to write P

        // p = exp(s - m) -> wave-private swizzled slab (C-layout write)
#pragma unroll
        for (int rf = 0; rf < 2; rf++)
#pragma unroll
            for (int j = 0; j < 4; j++) {
                int col = j * 16 + l15;
                int gc  = col >> 3;
#pragma unroll
                for (int r = 0; r < 4; r++) {
                    int m  = rf * 16 + quad * 4 + r;
                    int gs = (gc ^ m) & 7;
                    float s = sacc[rf][j][r];
                    float p = (s > -1e29f) ? __expf(s - mrow[rf][r]) : 0.f;
                    Pw[m * 64 + gs * 8 + (col & 7)] = (_Float16)p;
                }
            }

        // O += P V ; l += P 1
#pragma unroll
        for (int kc = 0; kc < 2; kc++) {
            half8 pf[2];
#pragma unroll
            for (int rf = 0; rf < 2; rf++) {
                int m  = rf * 16 + l15;
                int gs = ((kc * 4 + quad) ^ m) & 7;
                pf[rf] = *(const half8*)&Pw[m * 64 + gs * 8];
            }
#pragma unroll
            for (int n = 0; n < 8; n++) {
                int r  = n * 16 + l15;
                int gs = ((kc * 4 + quad) ^ r) & 7;
                half8 vf = *(const half8*)&Vs[r * 64 + gs * 8];
#pragma unroll
                for (int rf = 0; rf < 2; rf++)
                    oacc[rf][n] = MFMA_F16(pf[rf], vf, oacc[rf][n]);
            }
#pragma unroll
            for (int rf = 0; rf < 2; rf++)
                lacc[rf] = MFMA_F16(pf[rf], onesv, lacc[rf]);
        }
    }

    // (m, l) sidecar
    if (l15 == 0) {
#pragma unroll
        for (int rf = 0; rf < 2; rf++)
#pragma unroll
            for (int r = 0; r < 4; r++) {
                int row = rowbase + rf * 16 + quad * 4 + r;
                ml[(size_t)z * BT + b * SEQ + row] = make_float2(mrow[rf][r], lacc[rf][r]);
            }
    }

    // Epilogue: repack O through LDS (swizzled), then full-line half8 stores.
    __syncthreads();   // all PV reads of Smem complete
#pragma unroll
    for (int rf = 0; rf < 2; rf++)
#pragma unroll
        for (int n = 0; n < 8; n++) {
            int col = n * 16 + l15;
            int gc  = col >> 3;
#pragma unroll
            for (int r = 0; r < 4; r++) {
                int row = wave * 32 + rf * 16 + quad * 4 + r;   // 0..127
                int gp  = (gc & 8) | ((gc ^ row) & 7);
                Smem[row * 128 + gp * 8 + (col & 7)] = (_Float16)oacc[rf][n][r];
            }
        }
    __syncthreads();
    {
        _Float16* Oz = Op + (size_t)z * BT * QD + ((size_t)(b * SEQ) + xt * 128) * QD;
#pragma unroll
        for (int c = 0; c < 8; c++) {
            int ci  = c * 256 + tid;        // 0..2047
            int row = ci >> 4;
            int gl  = ci & 15;
            int gp  = (gl & 8) | ((gl ^ row) & 7);
            *(half8*)&Oz[(size_t)row * QD + gl * 8] = *(const half8*)&Smem[row * 128 + gp * 8];
        }
    }
}

// ---------------------------------------------------------------------------
// Merge NSPLIT fp16 partials. 16 threads/row, 8 cols each.
// ---------------------------------------------------------------------------
__global__ __launch_bounds__(256) void merge_kernel(
    const _Float16* __restrict__ Op,
    const float2* __restrict__ ml,
    float* __restrict__ out)
{
    int gid = blockIdx.x * 256 + threadIdx.x;
    int row = gid >> 4;
    int c8  = (gid & 15) * 8;

    float2 a[NSPLIT];
    float m = -3.0e38f;
#pragma unroll
    for (int s = 0; s < NSPLIT; s++) { a[s] = ml[(size_t)s * BT + row]; m = fmaxf(m, a[s].x); }
    float sc[NSPLIT];
    float denom = 0.f;
#pragma unroll
    for (int s = 0; s < NSPLIT; s++) { sc[s] = __expf(a[s].x - m); denom += sc[s] * a[s].y; }
    float inv = (denom > 0.f) ? (1.0f / denom) : 0.f;

    float acc[8] = {0, 0, 0, 0, 0, 0, 0, 0};
#pragma unroll
    for (int s = 0; s < NSPLIT; s++) {
        half8 o = *(const half8*)&Op[(size_t)s * BT * QD + (size_t)row * QD + c8];
#pragma unroll
        for (int e = 0; e < 8; e++) acc[e] += (float)o[e] * sc[s];
    }
    float4 lo = make_float4(acc[0] * inv, acc[1] * inv, acc[2] * inv, acc[3] * inv);
    float4 hi = make_float4(acc[4] * inv, acc[5] * inv, acc[6] * inv, acc[7] * inv);
    *(float4*)&out[(size_t)row * QD + c8] = lo;
    *(float4*)&out[(size_t)row * QD + c8 + 4] = hi;
}

extern "C" void kernel_launch(void* const* d_in, const int* in_sizes, int n_in,
                              void* d_out, int out_size, void* d_ws, size_t ws_size,
                              hipStream_t stream) {
    const float* x    = (const float*)d_in[0];
    const int*   mask = (const int*)d_in[1];
    const float* Wq   = (const float*)d_in[2];
    const float* Wk   = (const float*)d_in[3];
    const float* Wv   = (const float*)d_in[4];
    float* out = (float*)d_out;

    char* p = (char*)d_ws;
    _Float16* xh  = (_Float16*)p; p += (size_t)BT * DIM * 2;        // 32 MB
    _Float16* Wh  = (_Float16*)p; p += (size_t)3 * QD * DIM * 2;    // 768 KB
    _Float16* qb  = (_Float16*)p; p += (size_t)BT * QD * 2;         // 4 MB
    _Float16* kb  = (_Float16*)p; p += (size_t)BT * QD * 2;         // 4 MB
    _Float16* vtb = (_Float16*)p; p += (size_t)BT * QD * 2;         // 4 MB
    _Float16* Op  = (_Float16*)p; p += (size_t)NSPLIT * BT * QD * 2;// 32 MB
    float2*   ml  = (float2*)p;                                     // 1 MB

    cvt_kernel<<<dim3((XN4 + WN4) / 256), 256, 0, stream>>>(x, Wq, Wk, Wv, xh, Wh);
    proj_kernel<<<dim3(BT / 64, 3), 256, 0, stream>>>(xh, Wh, qb, kb, vtb);
    attn_kernel<<<dim3(16 * BATCH * NSPLIT), 256, 0, stream>>>(qb, kb, vtb, mask, Op, ml);
    merge_kernel<<<dim3(BT * 16 / 256), 256, 0, stream>>>(Op, ml, out);
}

// Round 7
// 168.701 us; speedup vs baseline: 1.5438x; 1.5112x over previous
//
#include <hip/hip_runtime.h>
#include <hip/hip_bf16.h>
#include <hip/hip_fp16.h>

typedef _Float16 half8 __attribute__((ext_vector_type(8)));
typedef _Float16 half4v __attribute__((ext_vector_type(4)));
typedef float float4v __attribute__((ext_vector_type(4)));

#define MFMA_F16(a, b, c) __builtin_amdgcn_mfma_f32_16x16x32_f16((a), (b), (c), 0, 0, 0)

// Async global->LDS DMA, 16B per lane. LDS dest = wave-uniform base + lane*16.
#define GLDS16(gp, lp) \
    __builtin_amdgcn_global_load_lds((const __attribute__((address_space(1))) unsigned int*)(gp), \
                                     (__attribute__((address_space(3))) unsigned int*)(lp), 16, 0, 0)

#define BATCH 8
#define SEQ   2048
#define DIM   1024
#define QD    128
#define BT    (BATCH * SEQ)          // 16384
#define NSPLIT 4
#define KSPAN (SEQ / NSPLIT)         // 512

// 16-lane all-lanes max reduction via DPP — pure VALU, stays off the LDS pipe.
__device__ __forceinline__ float dpp_max16(float x) {
    int v;
    v = __builtin_amdgcn_update_dpp(0, __float_as_int(x), 0xB1, 0xF, 0xF, false);  // quad_perm [1,0,3,2]
    x = fmaxf(x, __int_as_float(v));
    v = __builtin_amdgcn_update_dpp(0, __float_as_int(x), 0x4E, 0xF, 0xF, false);  // quad_perm [2,3,0,1]
    x = fmaxf(x, __int_as_float(v));
    v = __builtin_amdgcn_update_dpp(0, __float_as_int(x), 0x141, 0xF, 0xF, false); // row_half_mirror
    x = fmaxf(x, __int_as_float(v));
    v = __builtin_amdgcn_update_dpp(0, __float_as_int(x), 0x140, 0xF, 0xF, false); // row_mirror
    x = fmaxf(x, __int_as_float(v));
    return x;
}

// ---------------------------------------------------------------------------
// fp32 -> fp16 convert for x and the three W's, one kernel (BW-bound).
// ---------------------------------------------------------------------------
#define XN4 (BT * DIM / 4)           // 4194304 float4s in x
#define WN4 (3 * QD * DIM / 4)       // 98304 float4s in Wq+Wk+Wv

__global__ __launch_bounds__(256) void cvt_kernel(
    const float* __restrict__ x,
    const float* __restrict__ Wq,
    const float* __restrict__ Wk,
    const float* __restrict__ Wv,
    _Float16* __restrict__ xh,
    _Float16* __restrict__ Wh)
{
    int i = blockIdx.x * 256 + threadIdx.x;
    if (i < XN4) {
        float4 f = ((const float4*)x)[i];
        half4v h = {(_Float16)f.x, (_Float16)f.y, (_Float16)f.z, (_Float16)f.w};
        ((half4v*)xh)[i] = h;
    } else {
        int j = i - XN4;                       // 0 .. WN4-1
        int which = j >> 15;                   // 32768 float4 per W
        int o = j & 32767;
        const float* src = (which == 0) ? Wq : ((which == 1) ? Wk : Wv);
        float4 f = ((const float4*)src)[o];
        half4v h = {(_Float16)f.x, (_Float16)f.y, (_Float16)f.z, (_Float16)f.w};
        ((half4v*)Wh)[j] = h;
    }
}

// ---------------------------------------------------------------------------
// Projection (R4 config): 64x128 tile, BK=64, global_load_lds staging into
// XOR-swizzled LDS. 1-D grid of 768 = exactly 3/CU; which = id%3 so the 3
// consecutive blocks share the same A-tile reads through L2.
// ---------------------------------------------------------------------------
__global__ __launch_bounds__(256, 3) void proj_kernel(
    const _Float16* __restrict__ xh,     // (B*T, 1024)
    const _Float16* __restrict__ Wh,     // 3 x (128, 1024)
    _Float16* __restrict__ q_out,        // (B*T, 128)
    _Float16* __restrict__ k_out,        // (B*T, 128)
    _Float16* __restrict__ vt_out)       // (B, 128, T)
{
    __shared__ _Float16 As[64 * 64];     // 8 KB, swizzled row-major 64 x 64
    __shared__ _Float16 Bs[128 * 64];    // 16 KB

    const int tid  = threadIdx.x;
    const int lane = tid & 63;
    const int wave = tid >> 6;
    const int quad = lane >> 4;
    const int l15  = lane & 15;
    const int wr   = wave >> 1;          // 0..1 : row half (32 rows)
    const int wc   = wave & 1;           // 0..1 : col half (64 cols)

    const int id    = blockIdx.x;        // 0..767
    const int which = id % 3;            // consecutive blocks share A tile
    const int mblk  = id / 3;            // 0..255
    const _Float16* W = Wh + (size_t)which * QD * DIM;
    const int row0 = mblk * 64;

    float4v acc[2][4];
#pragma unroll
    for (int rf = 0; rf < 2; rf++)
#pragma unroll
        for (int n = 0; n < 4; n++)
            acc[rf][n] = (float4v){0.f, 0.f, 0.f, 0.f};

    for (int kk = 0; kk < DIM; kk += 64) {
        __syncthreads();
        // A: 512 chunks of 16B; 2 DMA calls per wave.
#pragma unroll
        for (int c = 0; c < 2; c++) {
            int ci = wave * 128 + c * 64 + lane;          // 0..511
            int r  = ci >> 3;
            int g  = (ci & 7) ^ (r & 7);                  // un-swizzle on the global side
            GLDS16(xh + (size_t)(row0 + r) * DIM + kk + g * 8, &As[(wave * 128 + c * 64) * 8]);
        }
        // B: 1024 chunks; 4 DMA calls per wave.
#pragma unroll
        for (int c = 0; c < 4; c++) {
            int ci = wave * 256 + c * 64 + lane;          // 0..1023
            int r  = ci >> 3;
            int g  = (ci & 7) ^ (r & 7);
            GLDS16(W + (size_t)r * DIM + kk + g * 8, &Bs[(wave * 256 + c * 64) * 8]);
        }
        __syncthreads();

        half8 af[2][2], bf[4][2];
#pragma unroll
        for (int rf = 0; rf < 2; rf++)
#pragma unroll
            for (int kc = 0; kc < 2; kc++) {
                int r = wr * 32 + rf * 16 + l15;
                int g = (kc * 4 + quad) ^ (r & 7);
                af[rf][kc] = *(const half8*)&As[r * 64 + g * 8];
            }
#pragma unroll
        for (int n = 0; n < 4; n++)
#pragma unroll
            for (int kc = 0; kc < 2; kc++) {
                int r = wc * 64 + n * 16 + l15;
                int g = (kc * 4 + quad) ^ (r & 7);
                bf[n][kc] = *(const half8*)&Bs[r * 64 + g * 8];
            }
#pragma unroll
        for (int kc = 0; kc < 2; kc++)
#pragma unroll
            for (int rf = 0; rf < 2; rf++)
#pragma unroll
                for (int n = 0; n < 4; n++)
                    acc[rf][n] = MFMA_F16(af[rf][kc], bf[n][kc], acc[rf][n]);
    }

    // Epilogue. C layout: col = l15, row = quad*4 + reg.
    if (which == 2) {
#pragma unroll
        for (int rf = 0; rf < 2; rf++) {
            int grow0 = row0 + wr * 32 + rf * 16 + quad * 4;
            int b  = grow0 >> 11;
            int t0 = grow0 & 2047;
#pragma unroll
            for (int n = 0; n < 4; n++) {
                int col = wc * 64 + n * 16 + l15;
                half4v h;
#pragma unroll
                for (int r = 0; r < 4; r++) h[r] = (_Float16)acc[rf][n][r];
                *(half4v*)&vt_out[((size_t)(b * QD + col)) * SEQ + t0] = h;
            }
        }
    } else {
        _Float16* out = (which == 0) ? q_out : k_out;
#pragma unroll
        for (int rf = 0; rf < 2; rf++) {
            int grow0 = row0 + wr * 32 + rf * 16 + quad * 4;
#pragma unroll
            for (int n = 0; n < 4; n++) {
                int col = wc * 64 + n * 16 + l15;
#pragma unroll
                for (int r = 0; r < 4; r++)
                    out[(size_t)(grow0 + r) * QD + col] = (_Float16)acc[rf][n][r];
            }
        }
    }
}

// ---------------------------------------------------------------------------
// Flash attention (R2/R4 locality regime): 3-D grid (xt, b, z), NSPLIT=4,
// consecutive-x blocks share the same K/V span via L2. Block = 128 q-rows
// (4 waves x 32), key blocks of 64. Separate P slab (no aliasing), 2 barriers
// per iter. GLDS+swizzle staging, DPP reductions, ones-column MFMA for l.
// Epilogue repacks O through LDS for full-line half8 stores.
// ---------------------------------------------------------------------------
__global__ __launch_bounds__(256, 2) void attn_kernel(
    const _Float16* __restrict__ q,    // (B*T, 128)
    const _Float16* __restrict__ k,    // (B*T, 128)
    const _Float16* __restrict__ vt,   // (B, 128, T)
    const int* __restrict__ mask,      // (B*T)
    _Float16* __restrict__ Op,         // (NSPLIT, B*T, 128)
    float2* __restrict__ ml)           // (NSPLIT, B*T)
{
    __shared__ _Float16 Smem[64 * 128 + 128 * 64 + 4 * 32 * 64];  // 48 KB
    __shared__ int Ms[64];
    _Float16* Ks = Smem;                   // 16 KB: keys x 128d, swizzled
    _Float16* Vs = Smem + 64 * 128;        // 16 KB: 128d x 64 keys, swizzled
    _Float16* Ps = Smem + 2 * 64 * 128;    // 16 KB: wave-private P slabs

    const int tid  = threadIdx.x;
    const int lane = tid & 63;
    const int wave = tid >> 6;
    const int quad = lane >> 4;
    const int l15  = lane & 15;

    const int xt = blockIdx.x;             // 0..15 (fastest -> K/V span sharing)
    const int b  = blockIdx.y;
    const int z  = blockIdx.z;
    const int rowbase = xt * 128 + wave * 32;

    half8 qf[2][4];
#pragma unroll
    for (int rf = 0; rf < 2; rf++) {
        const _Float16* qrow = q + ((size_t)(b * SEQ + rowbase + rf * 16 + l15)) * QD + quad * 8;
#pragma unroll
        for (int kc = 0; kc < 4; kc++)
            qf[rf][kc] = *(const half8*)(qrow + kc * 32);
    }

    const half8 onesv = {(_Float16)1, (_Float16)1, (_Float16)1, (_Float16)1,
                         (_Float16)1, (_Float16)1, (_Float16)1, (_Float16)1};

    float4v oacc[2][8];
#pragma unroll
    for (int rf = 0; rf < 2; rf++)
#pragma unroll
        for (int n = 0; n < 8; n++)
            oacc[rf][n] = (float4v){0.f, 0.f, 0.f, 0.f};
    float4v lacc[2] = {(float4v){0.f, 0.f, 0.f, 0.f}, (float4v){0.f, 0.f, 0.f, 0.f}};
    float mrow[2][4];
#pragma unroll
    for (int rf = 0; rf < 2; rf++)
#pragma unroll
        for (int r = 0; r < 4; r++) mrow[rf][r] = -1e30f;

    _Float16* Pw = &Ps[wave * 32 * 64];    // wave-private 4 KB slab

    for (int sb = z * KSPAN; sb < z * KSPAN + KSPAN; sb += 64) {
        __syncthreads();   // prior iter's reads of Ks/Vs complete
        // K: 64 keys x 128d = 1024 chunks; 4 DMA/wave, swizzled dest.
#pragma unroll
        for (int c = 0; c < 4; c++) {
            int ci = wave * 256 + c * 64 + lane;
            int r  = ci >> 4;                       // key
            int gs = ci & 15;
            int g  = (gs & 8) | ((gs ^ r) & 7);
            GLDS16(k + ((size_t)(b * SEQ + sb + r)) * QD + g * 8, &Ks[(wave * 256 + c * 64) * 8]);
        }
        // V^T: 128d x 64 keys = 1024 chunks; 4 DMA/wave.
#pragma unroll
        for (int c = 0; c < 4; c++) {
            int ci = wave * 256 + c * 64 + lane;
            int r  = ci >> 3;                       // d
            int g  = ((ci & 7) ^ r) & 7;
            GLDS16(vt + ((size_t)(b * QD + r)) * SEQ + sb + g * 8, &Vs[(wave * 256 + c * 64) * 8]);
        }
        if (tid < 64) Ms[tid] = mask[b * SEQ + sb + tid];
        __syncthreads();   // staging visible

        // S = Q K^T : 32 rows x 64 keys per wave, C layout
        float4v sacc[2][4];
#pragma unroll
        for (int rf = 0; rf < 2; rf++)
#pragma unroll
            for (int j = 0; j < 4; j++)
                sacc[rf][j] = (float4v){0.f, 0.f, 0.f, 0.f};
#pragma unroll
        for (int kc = 0; kc < 4; kc++) {
            half8 kf[4];
#pragma unroll
            for (int j = 0; j < 4; j++) {
                int r  = j * 16 + l15;
                int g  = kc * 4 + quad;
                int gs = (g & 8) | ((g ^ r) & 7);
                kf[j] = *(const half8*)&Ks[r * 128 + gs * 8];
            }
#pragma unroll
            for (int rf = 0; rf < 2; rf++)
#pragma unroll
                for (int j = 0; j < 4; j++)
                    sacc[rf][j] = MFMA_F16(qf[rf][kc], kf[j], sacc[rf][j]);
        }

        // mask + row-max + online-softmax scale (register/DPP only)
        float alpha[2][4];
#pragma unroll
        for (int rf = 0; rf < 2; rf++) {
            float rmax[4] = {-1e30f, -1e30f, -1e30f, -1e30f};
#pragma unroll
            for (int j = 0; j < 4; j++) {
                bool m_ok = (Ms[j * 16 + l15] != 0);
#pragma unroll
                for (int r = 0; r < 4; r++) {
                    float s = m_ok ? sacc[rf][j][r] : -1e30f;
                    sacc[rf][j][r] = s;
                    rmax[r] = fmaxf(rmax[r], s);
                }
            }
#pragma unroll
            for (int r = 0; r < 4; r++) {
                float rm = dpp_max16(rmax[r]);
                float mnew = fmaxf(mrow[rf][r], rm);
                alpha[rf][r] = __expf(mrow[rf][r] - mnew);
                mrow[rf][r] = mnew;
            }
        }

        // p = exp(s - m) -> wave-private swizzled slab (no barrier needed)
#pragma unroll
        for (int rf = 0; rf < 2; rf++)
#pragma unroll
            for (int j = 0; j < 4; j++) {
                int col = j * 16 + l15;
                int gc  = col >> 3;
#pragma unroll
                for (int r = 0; r < 4; r++) {
                    int m  = rf * 16 + quad * 4 + r;
                    int gs = (gc ^ m) & 7;
                    float s = sacc[rf][j][r];
                    float p = (s > -1e29f) ? __expf(s - mrow[rf][r]) : 0.f;
                    Pw[m * 64 + gs * 8 + (col & 7)] = (_Float16)p;
                }
            }

        // rescale accumulators
#pragma unroll
        for (int rf = 0; rf < 2; rf++) {
#pragma unroll
            for (int n = 0; n < 8; n++)
#pragma unroll
                for (int r = 0; r < 4; r++)
                    oacc[rf][n][r] *= alpha[rf][r];
#pragma unroll
            for (int r = 0; r < 4; r++) lacc[rf][r] *= alpha[rf][r];
        }

        // O += P V ; l += P 1
#pragma unroll
        for (int kc = 0; kc < 2; kc++) {
            half8 pf[2];
#pragma unroll
            for (int rf = 0; rf < 2; rf++) {
                int m  = rf * 16 + l15;
                int gs = ((kc * 4 + quad) ^ m) & 7;
                pf[rf] = *(const half8*)&Pw[m * 64 + gs * 8];
            }
#pragma unroll
            for (int n = 0; n < 8; n++) {
                int r  = n * 16 + l15;
                int gs = ((kc * 4 + quad) ^ r) & 7;
                half8 vf = *(const half8*)&Vs[r * 64 + gs * 8];
#pragma unroll
                for (int rf = 0; rf < 2; rf++)
                    oacc[rf][n] = MFMA_F16(pf[rf], vf, oacc[rf][n]);
            }
#pragma unroll
            for (int rf = 0; rf < 2; rf++)
                lacc[rf] = MFMA_F16(pf[rf], onesv, lacc[rf]);
        }
    }

    // (m, l) sidecar
    if (l15 == 0) {
#pragma unroll
        for (int rf = 0; rf < 2; rf++)
#pragma unroll
            for (int r = 0; r < 4; r++) {
                int row = rowbase + rf * 16 + quad * 4 + r;
                ml[(size_t)z * BT + b * SEQ + row] = make_float2(mrow[rf][r], lacc[rf][r]);
            }
    }

    // Epilogue: repack O (128 rows x 128 cols) through Ks/Vs region (32 KB),
    // then full-line half8 stores.
    __syncthreads();   // all PV reads of Smem complete
#pragma unroll
    for (int rf = 0; rf < 2; rf++)
#pragma unroll
        for (int n = 0; n < 8; n++) {
            int col = n * 16 + l15;
            int gc  = col >> 3;
#pragma unroll
            for (int r = 0; r < 4; r++) {
                int row = wave * 32 + rf * 16 + quad * 4 + r;   // 0..127
                int gp  = (gc & 8) | ((gc ^ row) & 7);
                Smem[row * 128 + gp * 8 + (col & 7)] = (_Float16)oacc[rf][n][r];
            }
        }
    __syncthreads();
    {
        _Float16* Oz = Op + (size_t)z * BT * QD + ((size_t)(b * SEQ) + xt * 128) * QD;
#pragma unroll
        for (int c = 0; c < 8; c++) {
            int ci  = c * 256 + tid;        // 0..2047
            int row = ci >> 4;
            int gl  = ci & 15;
            int gp  = (gl & 8) | ((gl ^ row) & 7);
            *(half8*)&Oz[(size_t)row * QD + gl * 8] = *(const half8*)&Smem[row * 128 + gp * 8];
        }
    }
}

// ---------------------------------------------------------------------------
// Merge NSPLIT fp16 partials. 16 threads/row, 8 cols each.
// ---------------------------------------------------------------------------
__global__ __launch_bounds__(256) void merge_kernel(
    const _Float16* __restrict__ Op,
    const float2* __restrict__ ml,
    float* __restrict__ out)
{
    int gid = blockIdx.x * 256 + threadIdx.x;
    int row = gid >> 4;
    int c8  = (gid & 15) * 8;

    float2 a[NSPLIT];
    float m = -3.0e38f;
#pragma unroll
    for (int s = 0; s < NSPLIT; s++) { a[s] = ml[(size_t)s * BT + row]; m = fmaxf(m, a[s].x); }
    float sc[NSPLIT];
    float denom = 0.f;
#pragma unroll
    for (int s = 0; s < NSPLIT; s++) { sc[s] = __expf(a[s].x - m); denom += sc[s] * a[s].y; }
    float inv = (denom > 0.f) ? (1.0f / denom) : 0.f;

    float acc[8] = {0, 0, 0, 0, 0, 0, 0, 0};
#pragma unroll
    for (int s = 0; s < NSPLIT; s++) {
        half8 o = *(const half8*)&Op[(size_t)s * BT * QD + (size_t)row * QD + c8];
#pragma unroll
        for (int e = 0; e < 8; e++) acc[e] += (float)o[e] * sc[s];
    }
    float4 lo = make_float4(acc[0] * inv, acc[1] * inv, acc[2] * inv, acc[3] * inv);
    float4 hi = make_float4(acc[4] * inv, acc[5] * inv, acc[6] * inv, acc[7] * inv);
    *(float4*)&out[(size_t)row * QD + c8] = lo;
    *(float4*)&out[(size_t)row * QD + c8 + 4] = hi;
}

extern "C" void kernel_launch(void* const* d_in, const int* in_sizes, int n_in,
                              void* d_out, int out_size, void* d_ws, size_t ws_size,
                              hipStream_t stream) {
    const float* x    = (const float*)d_in[0];
    const int*   mask = (const int*)d_in[1];
    const float* Wq   = (const float*)d_in[2];
    const float* Wk   = (const float*)d_in[3];
    const float* Wv   = (const float*)d_in[4];
    float* out = (float*)d_out;

    char* p = (char*)d_ws;
    _Float16* xh  = (_Float16*)p; p += (size_t)BT * DIM * 2;        // 32 MB
    _Float16* Wh  = (_Float16*)p; p += (size_t)3 * QD * DIM * 2;    // 768 KB
    _Float16* qb  = (_Float16*)p; p += (size_t)BT * QD * 2;         // 4 MB
    _Float16* kb  = (_Float16*)p; p += (size_t)BT * QD * 2;         // 4 MB
    _Float16* vtb = (_Float16*)p; p += (size_t)BT * QD * 2;         // 4 MB
    _Float16* Op  = (_Float16*)p; p += (size_t)NSPLIT * BT * QD * 2;// 16 MB
    float2*   ml  = (float2*)p;                                     // 512 KB

    cvt_kernel<<<dim3((XN4 + WN4) / 256), 256, 0, stream>>>(x, Wq, Wk, Wv, xh, Wh);
    proj_kernel<<<dim3(768), 256, 0, stream>>>(xh, Wh, qb, kb, vtb);
    attn_kernel<<<dim3(SEQ / 128, BATCH, NSPLIT), 256, 0, stream>>>(qb, kb, vtb, mask, Op, ml);
    merge_kernel<<<dim3(BT * 16 / 256), 256, 0, stream>>>(Op, ml, out);
}